// Round 3
// baseline (169.630 us; speedup 1.0000x reference)
//
#include <hip/hip_runtime.h>
#include <math.h>

#define T_DIM 12

// One thread processes ONE column (float2 = (x,y) per t).
// Arrays are (T, N, 2) f32 -> row stride in float2 units is N.
// All 24 loads staged into registers and pinned before compute via
// sched_barrier(0) so the full 12 KB/wave stays in flight (MLP).
// Curvature mask computed sqrt/div-free: |k|>=1  <=>  4*area^2 >= dist^2.
__global__ __launch_bounds__(256) void ade_traj_kernel(
    const float2* __restrict__ inp,
    const float2* __restrict__ tgt,
    int n,                    // N columns
    float* __restrict__ ws)   // ws[0] = sum(ade*sel), ws[1] = cnt
{
    const int i = blockIdx.x * blockDim.x + threadIdx.x;
    float num = 0.0f;
    float cnt = 0.0f;

    if (i < n) {
        // ---- stage ALL loads (static indexing -> registers) ----
        float2 tv[T_DIM];
        float2 iv[T_DIM];
        #pragma unroll
        for (int t = 0; t < T_DIM; ++t) tv[t] = tgt[t * n + i];
        #pragma unroll
        for (int t = 0; t < T_DIM; ++t) iv[t] = inp[t * n + i];
        // pin: no compute may hoist above, no load may sink below
        __builtin_amdgcn_sched_barrier(0);

        // ---- ADE: mean over t of ||inp - tgt|| ----
        float ade = 0.0f;
        #pragma unroll
        for (int t = 0; t < T_DIM; ++t) {
            float dx = iv[t].x - tv[t].x, dy = iv[t].y - tv[t].y;
            ade += __builtin_amdgcn_sqrtf(dx * dx + dy * dy);
        }

        // ---- Menger curvature mask + run-length stats (sqrt/div-free) ----
        float run = 0.0f, mx = 0.0f, sm = 0.0f;
        #pragma unroll
        for (int t = 2; t < T_DIM; ++t) {
            float ax = tv[t-2].x, ay = tv[t-2].y;
            float bx = tv[t-1].x, by = tv[t-1].y;
            float cx = tv[t].x,   cy = tv[t].y;
            // signed twice-area
            float ar = ax * (by - cy) + bx * (cy - ay) + cx * (ay - by);
            float a2 = 4.0f * ar * ar;                     // (2*area)^2
            float ex, ey;
            ex = bx - ax; ey = by - ay; float e01 = ex * ex + ey * ey;
            ex = cx - bx; ey = cy - by; float e12 = ex * ex + ey * ey;
            ex = cx - ax; ey = cy - ay; float e02 = ex * ex + ey * ey;
            float d2 = e01 * e12 * e02;                    // dist^2
            // |k| >= 1  <=>  2|area| >= dist  <=>  a2 >= d2  (both >= 0)
            // NaN corner (0/0): reference maps k=NaN -> 0 -> mask 0.
            // inf corner (area>0, dist=0): |inf| >= 1 -> mask 1.  Both handled:
            float m = ((a2 >= d2) && !(d2 == 0.0f && a2 == 0.0f)) ? 1.0f : 0.0f;
            run += m;
            mx = fmaxf(mx, run);
            run *= m;
            sm += m;
        }

        // criteria = (mx>=3) & (mx<11) & (sm>0); mx<=10 so (mx<11) is vacuous
        bool sel = (mx >= 3.0f) && (sm > 0.0f);
        if (sel) { num = ade * (1.0f / 12.0f); cnt = 1.0f; }
    }

    // wave(64) shuffle reduction
    #pragma unroll
    for (int off = 32; off > 0; off >>= 1) {
        num += __shfl_down(num, off, 64);
        cnt += __shfl_down(cnt, off, 64);
    }

    __shared__ float snum[4], scnt[4];
    const int wave = threadIdx.x >> 6;
    const int lane = threadIdx.x & 63;
    if (lane == 0) { snum[wave] = num; scnt[wave] = cnt; }
    __syncthreads();
    if (threadIdx.x == 0) {
        float nsum = 0.0f, csum = 0.0f;
        #pragma unroll
        for (int w = 0; w < 4; ++w) { nsum += snum[w]; csum += scnt[w]; }
        atomicAdd(&ws[0], nsum);
        atomicAdd(&ws[1], csum);
    }
}

__global__ void ade_traj_finalize(const float* __restrict__ ws, float* __restrict__ out)
{
    if (threadIdx.x == 0 && blockIdx.x == 0) {
        float s = ws[0];
        float c = ws[1];
        out[0] = (c > 0.0f) ? (s / fmaxf(c, 1.0f)) : 0.0f;
    }
}

extern "C" void kernel_launch(void* const* d_in, const int* in_sizes, int n_in,
                              void* d_out, int out_size, void* d_ws, size_t ws_size,
                              hipStream_t stream) {
    const float* inp = (const float*)d_in[0];
    const float* tgt = (const float*)d_in[1];
    float* out = (float*)d_out;
    float* ws  = (float*)d_ws;

    // in_sizes[0] = T*N*2
    const int total = in_sizes[0];
    const int N = total / (T_DIM * 2);      // 1,500,000

    // zero the two accumulators every launch (ws is poisoned once, never restored)
    hipMemsetAsync(ws, 0, 2 * sizeof(float), stream);

    const int block = 256;
    const int grid = (N + block - 1) / block;   // ~5860 blocks
    ade_traj_kernel<<<grid, block, 0, stream>>>(
        (const float2*)inp, (const float2*)tgt, N, ws);
    ade_traj_finalize<<<1, 64, 0, stream>>>(ws, out);
}

// Round 4
// 52.712 us; speedup vs baseline: 3.2180x; 3.2180x over previous
//
#include <hip/hip_runtime.h>
#include <math.h>

#define T_DIM 12
#define GRID_BLOCKS 2048

// One thread processes TWO adjacent columns (a = .x/.y, b = .z/.w of a float4).
// Arrays are (T, N, 2) f32 -> row stride in float4 units is N/2.
// NO global atomics: per-block partials go to distinct ws slots (plain store),
// a second 1-block kernel reduces them. (Same-address device atomics across
// 8 XCDs were the R1-R3 bottleneck: L3-warm replays timed identical to cold.)
__global__ __launch_bounds__(256) void ade_traj_kernel(
    const float4* __restrict__ inp,
    const float4* __restrict__ tgt,
    int npairs,                    // N/2
    float2* __restrict__ partials) // partials[blockIdx] = (num, cnt)
{
    const int stride = gridDim.x * blockDim.x;
    float num = 0.0f;
    float cnt = 0.0f;

    for (int i = blockIdx.x * blockDim.x + threadIdx.x; i < npairs; i += stride) {
        float ade_a = 0.0f, ade_b = 0.0f;
        float run_a = 0.0f, mx_a = 0.0f, sm_a = 0.0f;
        float run_b = 0.0f, mx_b = 0.0f, sm_b = 0.0f;
        float p0ax = 0.f, p0ay = 0.f, p1ax = 0.f, p1ay = 0.f;
        float p0bx = 0.f, p0by = 0.f, p1bx = 0.f, p1by = 0.f;

        #pragma unroll
        for (int t = 0; t < T_DIM; ++t) {
            const int off = t * npairs + i;
            float4 tv = tgt[off];
            float4 iv = inp[off];

            // ADE contribution
            {
                float dx = iv.x - tv.x, dy = iv.y - tv.y;
                ade_a += __builtin_amdgcn_sqrtf(dx * dx + dy * dy);
                float dxb = iv.z - tv.z, dyb = iv.w - tv.w;
                ade_b += __builtin_amdgcn_sqrtf(dxb * dxb + dyb * dyb);
            }

            if (t >= 2) {
                // Menger mask, sqrt/div-free: |k|>=1 <=> (2*area)^2 >= dist^2.
                // NaN corner (0/0 -> k=NaN -> mask 0) handled explicitly;
                // inf corner (area>0, dist=0 -> mask 1) falls out of a2>=d2.
                {
                    float cx = tv.x, cy = tv.y;
                    float ar = p0ax * (p1ay - cy) + p1ax * (cy - p0ay) + cx * (p0ay - p1ay);
                    float a2 = 4.0f * ar * ar;
                    float ex, ey;
                    ex = p1ax - p0ax; ey = p1ay - p0ay; float e01 = ex * ex + ey * ey;
                    ex = cx - p1ax;   ey = cy - p1ay;   float e12 = ex * ex + ey * ey;
                    ex = cx - p0ax;   ey = cy - p0ay;   float e02 = ex * ex + ey * ey;
                    float d2 = e01 * e12 * e02;
                    float m = ((a2 >= d2) && !(d2 == 0.0f && a2 == 0.0f)) ? 1.0f : 0.0f;
                    run_a += m;
                    mx_a = fmaxf(mx_a, run_a);
                    run_a *= m;
                    sm_a += m;
                }
                {
                    float cx = tv.z, cy = tv.w;
                    float ar = p0bx * (p1by - cy) + p1bx * (cy - p0by) + cx * (p0by - p1by);
                    float a2 = 4.0f * ar * ar;
                    float ex, ey;
                    ex = p1bx - p0bx; ey = p1by - p0by; float e01 = ex * ex + ey * ey;
                    ex = cx - p1bx;   ey = cy - p1by;   float e12 = ex * ex + ey * ey;
                    ex = cx - p0bx;   ey = cy - p0by;   float e02 = ex * ex + ey * ey;
                    float d2 = e01 * e12 * e02;
                    float m = ((a2 >= d2) && !(d2 == 0.0f && a2 == 0.0f)) ? 1.0f : 0.0f;
                    run_b += m;
                    mx_b = fmaxf(mx_b, run_b);
                    run_b *= m;
                    sm_b += m;
                }
            }
            p0ax = p1ax; p0ay = p1ay; p1ax = tv.x; p1ay = tv.y;
            p0bx = p1bx; p0by = p1by; p1bx = tv.z; p1by = tv.w;
        }

        // criteria = (mx>=3) & (mx<11) & (sm>0); mx<=10 so (mx<11) vacuous
        bool sel_a = (mx_a >= 3.0f) && (sm_a > 0.0f);
        bool sel_b = (mx_b >= 3.0f) && (sm_b > 0.0f);
        if (sel_a) { num += ade_a * (1.0f / 12.0f); cnt += 1.0f; }
        if (sel_b) { num += ade_b * (1.0f / 12.0f); cnt += 1.0f; }
    }

    // wave(64) shuffle reduction
    #pragma unroll
    for (int off = 32; off > 0; off >>= 1) {
        num += __shfl_down(num, off, 64);
        cnt += __shfl_down(cnt, off, 64);
    }

    __shared__ float snum[4], scnt[4];
    const int wave = threadIdx.x >> 6;
    const int lane = threadIdx.x & 63;
    if (lane == 0) { snum[wave] = num; scnt[wave] = cnt; }
    __syncthreads();
    if (threadIdx.x == 0) {
        float n = 0.0f, c = 0.0f;
        #pragma unroll
        for (int w = 0; w < 4; ++w) { n += snum[w]; c += scnt[w]; }
        partials[blockIdx.x] = make_float2(n, c);   // plain store, unique slot
    }
}

__global__ __launch_bounds__(256) void ade_traj_finalize(
    const float2* __restrict__ partials, int g, float* __restrict__ out)
{
    float n = 0.0f, c = 0.0f;
    for (int j = threadIdx.x; j < g; j += 256) {
        float2 p = partials[j];
        n += p.x; c += p.y;
    }
    #pragma unroll
    for (int off = 32; off > 0; off >>= 1) {
        n += __shfl_down(n, off, 64);
        c += __shfl_down(c, off, 64);
    }
    __shared__ float sn[4], sc[4];
    const int wave = threadIdx.x >> 6;
    const int lane = threadIdx.x & 63;
    if (lane == 0) { sn[wave] = n; sc[wave] = c; }
    __syncthreads();
    if (threadIdx.x == 0) {
        float ns = 0.0f, cs = 0.0f;
        #pragma unroll
        for (int w = 0; w < 4; ++w) { ns += sn[w]; cs += sc[w]; }
        out[0] = (cs > 0.0f) ? (ns / fmaxf(cs, 1.0f)) : 0.0f;
    }
}

extern "C" void kernel_launch(void* const* d_in, const int* in_sizes, int n_in,
                              void* d_out, int out_size, void* d_ws, size_t ws_size,
                              hipStream_t stream) {
    const float* inp = (const float*)d_in[0];
    const float* tgt = (const float*)d_in[1];
    float* out = (float*)d_out;
    float2* partials = (float2*)d_ws;    // GRID_BLOCKS float2 slots, all written each launch

    const int total = in_sizes[0];       // T*N*2
    const int N = total / (T_DIM * 2);   // 1,500,000
    const int npairs = N / 2;            // 750,000

    ade_traj_kernel<<<GRID_BLOCKS, 256, 0, stream>>>(
        (const float4*)inp, (const float4*)tgt, npairs, partials);
    ade_traj_finalize<<<1, 256, 0, stream>>>(partials, GRID_BLOCKS, out);
}